// Round 5
// baseline (735.034 us; speedup 1.0000x reference)
//
#include <hip/hip_runtime.h>
#include <stdint.h>

// Problem dims
#define B_  32
#define T_  512
#define DE_ 512
#define H_  640
#define V_  4096
#define J_  640

typedef __attribute__((ext_vector_type(4))) float  f32x4;
typedef __attribute__((ext_vector_type(8))) __bf16 bf16x8;

typedef __attribute__((address_space(3))) void LdsV;
typedef __attribute__((address_space(1))) void GloV;

__device__ __forceinline__ unsigned short f2bf(float f) {
    uint32_t u = __builtin_bit_cast(uint32_t, f);
    u += 0x7fffu + ((u >> 16) & 1u);   // round-to-nearest-even
    return (unsigned short)(u >> 16);
}

// raw barrier with compiler fence (no implicit vmcnt(0) drain, unlike __syncthreads)
__device__ __forceinline__ void sbar() { asm volatile("s_barrier" ::: "memory"); }

// ---------------- fp32 -> bf16 elementwise convert ----------------
__global__ void conv_f32_bf16_k(const float* __restrict__ src,
                                unsigned short* __restrict__ dst, int n) {
    int i = blockIdx.x * blockDim.x + threadIdx.x;
    if (i < n) dst[i] = f2bf(src[i]);
}

// ---------------- encoder (B,D,T) -> bf16 (B*T, D) transpose ----------------
__global__ void enc_transpose_k(const float* __restrict__ enc,
                                unsigned short* __restrict__ out) {
    __shared__ float tile[32][33];
    int b  = blockIdx.z;
    int t0 = blockIdx.x * 32, d0 = blockIdx.y * 32;
    int tx = threadIdx.x & 31;
    int ty = (threadIdx.x >> 5) * 4;
    const float* src = enc + ((size_t)b * DE_ + d0) * T_ + t0;
#pragma unroll
    for (int i = 0; i < 4; i++)
        tile[ty + i][tx] = src[(size_t)(ty + i) * T_ + tx];  // coalesced over t
    __syncthreads();
    unsigned short* dst = out + ((size_t)b * T_ + t0) * DE_ + d0;
#pragma unroll
    for (int i = 0; i < 4; i++)
        dst[(size_t)(ty + i) * DE_ + tx] = f2bf(tile[tx][ty + i]);  // coalesced over d
}

// ---------------- LSTM gates: gates[b][n] = x_b . wih[n] + h_b . whh[n] + biases ----------------
__global__ void lstm_gates_k(const float* __restrict__ x, const int* __restrict__ tok,
                             const float* __restrict__ emb, const float* __restrict__ h,
                             const float* __restrict__ wih, const float* __restrict__ whh,
                             const float* __restrict__ bih, const float* __restrict__ bhh,
                             float* __restrict__ gates) {
    int n = blockIdx.x, lane = threadIdx.x;
    float wi[10], wh[10];
#pragma unroll
    for (int i = 0; i < 10; i++) {
        wi[i] = wih[(size_t)n * H_ + lane + 64 * i];   // coalesced
        wh[i] = whh[(size_t)n * H_ + lane + 64 * i];
    }
    float bias = bih[n] + bhh[n];
    for (int b = 0; b < B_; b++) {
        const float* xr = tok ? (emb + (size_t)tok[b] * H_) : (x + (size_t)b * H_);
        const float* hr = h + (size_t)b * H_;
        float s = 0.f;
#pragma unroll
        for (int i = 0; i < 10; i++)
            s += wi[i] * xr[lane + 64 * i] + wh[i] * hr[lane + 64 * i];
#pragma unroll
        for (int off = 32; off > 0; off >>= 1)
            s += __shfl_down(s, off, 64);
        if (lane == 0) gates[(size_t)b * (4 * H_) + n] = s + bias;
    }
}

// ---------------- LSTM pointwise update (+ optional target_length passthrough) ----------------
__global__ void lstm_update_k(const float* __restrict__ gates, const float* __restrict__ c_in,
                              float* __restrict__ h_out, float* __restrict__ c_out,
                              const int* __restrict__ tlen, float* __restrict__ tlen_out) {
    int idx = blockIdx.x * blockDim.x + threadIdx.x;
    if (tlen_out != nullptr && idx < B_) tlen_out[idx] = (float)tlen[idx];
    if (idx >= B_ * H_) return;
    int b = idx / H_, j = idx - b * H_;
    const float* gr = gates + (size_t)b * 4 * H_;
    float ig = 1.f / (1.f + expf(-gr[j]));
    float fg = 1.f / (1.f + expf(-gr[H_ + j]));
    float gg = tanhf(gr[2 * H_ + j]);
    float og = 1.f / (1.f + expf(-gr[3 * H_ + j]));
    float c  = fg * c_in[idx] + ig * gg;
    h_out[idx] = og * tanhf(c);
    c_out[idx] = c;
}

// ---------------- g[b][j] = h1_b . wpred[j] + bpred[j] ----------------
__global__ void pred_g_k(const float* __restrict__ h1, const float* __restrict__ wp,
                         const float* __restrict__ bp, float* __restrict__ g) {
    int j = blockIdx.x, lane = threadIdx.x;
    float w[10];
#pragma unroll
    for (int i = 0; i < 10; i++) w[i] = wp[(size_t)j * H_ + lane + 64 * i];
    for (int b = 0; b < B_; b++) {
        const float* hr = h1 + (size_t)b * H_;
        float s = 0.f;
#pragma unroll
        for (int i = 0; i < 10; i++) s += w[i] * hr[lane + 64 * i];
#pragma unroll
        for (int off = 32; off > 0; off >>= 1)
            s += __shfl_down(s, off, 64);
        if (lane == 0) g[(size_t)b * J_ + j] = s + bp[j];
    }
}

// ---------------- m97-style bf16 MFMA GEMM, C = A (MxK) * B^T (NxK) ----------------
// Used for GEMM1 (N=640 not divisible by 256).
template <int K, int EPI>
__global__ __launch_bounds__(256) void gemm_bt_k(
        const unsigned short* __restrict__ A, const unsigned short* __restrict__ Bm,
        const float* __restrict__ bias, const float* __restrict__ g,
        float* __restrict__ outF, unsigned short* __restrict__ outU, int ldn) {
    __shared__ __align__(16) unsigned short As[128 * 32];
    __shared__ __align__(16) unsigned short Bs[128 * 32];
    const int tid  = threadIdx.x;
    const int w    = tid >> 6;          // wave 0..3
    const int lane = tid & 63;
    const int tile_n = blockIdx.x * 128;
    const int tile_m = blockIdx.y * 128;
    const int wm = w & 1, wn = w >> 1;  // wave -> 64x64 quadrant
    const int l15 = lane & 15, quad = lane >> 4;
    const int lr = lane >> 2, lc = lane & 3;  // staging: row-in-chunk, 16B slot

    f32x4 zero = {0.f, 0.f, 0.f, 0.f};
    f32x4 acc[4][4];
#pragma unroll
    for (int i = 0; i < 4; i++)
#pragma unroll
        for (int j = 0; j < 4; j++) acc[i][j] = zero;

    for (int k0 = 0; k0 < K; k0 += 32) {
#pragma unroll
        for (int cc = 0; cc < 2; cc++) {
            const int c = 2 * w + cc;
            const char* ga = (const char*)(A + (size_t)(tile_m + 16 * c + lr) * K)
                             + (size_t)k0 * 2 + lc * 16;
            __builtin_amdgcn_global_load_lds((const GloV*)ga,
                    (LdsV*)((char*)As + c * 1024), 16, 0, 0);
            const char* gb = (const char*)(Bm + (size_t)(tile_n + 16 * c + lr) * K)
                             + (size_t)k0 * 2 + lc * 16;
            __builtin_amdgcn_global_load_lds((const GloV*)gb,
                    (LdsV*)((char*)Bs + c * 1024), 16, 0, 0);
        }
        __syncthreads();

        bf16x8 av[4], bv[4];
#pragma unroll
        for (int i = 0; i < 4; i++) {
            av[i] = *(const bf16x8*)&As[(wm * 64 + i * 16 + l15) * 32 + quad * 8];
            bv[i] = *(const bf16x8*)&Bs[(wn * 64 + i * 16 + l15) * 32 + quad * 8];
        }
#pragma unroll
        for (int i = 0; i < 4; i++)
#pragma unroll
            for (int j = 0; j < 4; j++)
                acc[i][j] = __builtin_amdgcn_mfma_f32_16x16x32_bf16(av[i], bv[j], acc[i][j], 0, 0, 0);
        __syncthreads();
    }

#pragma unroll
    for (int i = 0; i < 4; i++) {
        const int mb = tile_m + wm * 64 + i * 16 + quad * 4;
#pragma unroll
        for (int j = 0; j < 4; j++) {
            const int n = tile_n + wn * 64 + j * 16 + l15;
#pragma unroll
            for (int r = 0; r < 4; r++) {
                float v = acc[i][j][r] + bias[n];
                if (EPI == 0) {
                    outF[(size_t)(mb + r) * ldn + n] = v;
                } else {
                    v += g[(size_t)((mb + r) >> 9) * J_ + n];
                    outU[(size_t)(mb + r) * ldn + n] = f2bf(fmaxf(v, 0.f));
                }
            }
        }
    }
}

// ---------------- 256x256 8-phase deep-pipeline bf16 GEMM (T1+T2+T3+T4+T5) ----------------
// BYTE-FROZEN from round 3/4 (t = 105.3 us measured by round-4 differential).
template <int M, int N, int K>
__global__ __launch_bounds__(512, 2) void gemm256_k(
        const unsigned short* __restrict__ A, const unsigned short* __restrict__ Bm,
        const float* __restrict__ bias, float* __restrict__ out) {
    __shared__ __align__(16) char lds[131072];   // A: [0,64K) dbuf; B: [64K,128K) dbuf
    constexpr int NT  = K / 64;
    constexpr int K2  = K * 2;                   // global row stride in bytes
    constexpr int NTN = N / 256;
    constexpr int NWG = (M / 256) * NTN;         // 1024 here (divisible by 8)

    // T1: XCD-aware bijective swizzle (NWG % 8 == 0)
    const int bid = blockIdx.x;
    const int swz = (bid & 7) * (NWG / 8) + (bid >> 3);
    const int tile_n = (swz % NTN) * 256;
    const int tile_m = (swz / NTN) * 256;

    const int tid  = threadIdx.x;
    const int w    = tid >> 6;                   // wave 0..7
    const int l    = tid & 63;
    const int wm   = w >> 2;                     // 0..1 -> 128-row half of C-tile
    const int wn   = w & 3;                      // 0..3 -> 64-col slice
    const int l15  = l & 15, quad = l >> 4;

    const int lrow = l >> 3;
    const int lcc  = (l & 7) ^ lrow;             // inverse-swizzled global col chunk
    const char* gAb = (const char*)A  + (size_t)tile_m * K2;
    const char* gBb = (const char*)Bm + (size_t)tile_n * K2;

    auto stageA = [&](int h, int kt) {   // half h of A K-tile kt -> buf (kt&1)
        char* d = lds + (kt & 1) * 32768 + h * 16384 + w * 2048;
        const char* s = gAb + (size_t)(h * 128 + w * 16 + lrow) * K2 + kt * 128 + lcc * 16;
        __builtin_amdgcn_global_load_lds((const GloV*)s, (LdsV*)d, 16, 0, 0);
        __builtin_amdgcn_global_load_lds((const GloV*)(s + (size_t)8 * K2),
                                         (LdsV*)(d + 1024), 16, 0, 0);
    };
    auto stageB = [&](int h, int kt) {
        char* d = lds + 65536 + (kt & 1) * 32768 + h * 16384 + w * 2048;
        const char* s = gBb + (size_t)(h * 128 + w * 16 + lrow) * K2 + kt * 128 + lcc * 16;
        __builtin_amdgcn_global_load_lds((const GloV*)s, (LdsV*)d, 16, 0, 0);
        __builtin_amdgcn_global_load_lds((const GloV*)(s + (size_t)8 * K2),
                                         (LdsV*)(d + 1024), 16, 0, 0);
    };

    const int colk0 = (quad * 16) ^ ((l15 & 7) << 4);   // kstep 0 (k 0..31)
    const int colk1 = colk0 ^ 64;                       // kstep 1 (k 32..63)
    const int arow  = wm * 16384 + l15 * 128;           // A frag base byte (within buf)
    const int brow  = wn * 8192 + l15 * 128;            // B frag base byte (within buf)

    f32x4 acc[8][4];
    f32x4 zero = {0.f, 0.f, 0.f, 0.f};
#pragma unroll
    for (int i = 0; i < 8; i++)
#pragma unroll
        for (int j = 0; j < 4; j++) acc[i][j] = zero;

    // prologue: tile 0 fully + B halves of tile 1 (per steady-state schedule).
    stageA(0, 0); stageA(1, 0); stageB(0, 0); stageB(1, 0);
    stageB(0, 1); stageB(1, 1);
    asm volatile("s_waitcnt vmcnt(4)" ::: "memory");   // tile 0's 8 loads landed
    sbar();

    for (int t = 0; t < NT; ++t) {
        const char* la = lds + (t & 1) * 32768;
        const char* lb = lds + 65536 + (t & 1) * 32768;

        bf16x8 bv0[4], bv1[4];
#pragma unroll
        for (int p = 0; p < 4; p++) {
            bf16x8 av[2][2];
            if (p == 0) {   // whole-K-tile B fragments -> regs (closes B-region reads)
#pragma unroll
                for (int j = 0; j < 4; j++) {
                    bv0[j] = *(const bf16x8*)(lb + brow + j * 2048 + colk0);
                    bv1[j] = *(const bf16x8*)(lb + brow + j * 2048 + colk1);
                }
            }
            av[0][0] = *(const bf16x8*)(la + arow + (2 * p) * 2048 + colk0);
            av[0][1] = *(const bf16x8*)(la + arow + (2 * p) * 2048 + colk1);
            av[1][0] = *(const bf16x8*)(la + arow + (2 * p + 1) * 2048 + colk0);
            av[1][1] = *(const bf16x8*)(la + arow + (2 * p + 1) * 2048 + colk1);

            // staging schedule (write-after-read safe)
            if (p == 0) {
                if (t + 1 < NT) stageA(0, t + 1);
                asm volatile("s_waitcnt lgkmcnt(8)" ::: "memory");
            } else if (p == 1) {
                if (t + 1 < NT) stageA(1, t + 1);
            } else if (p == 2) {
                if (t + 2 < NT) stageB(0, t + 2);
            } else {
                if (t + 2 < NT) stageB(1, t + 2);
            }

            sbar();
            asm volatile("s_waitcnt lgkmcnt(0)" ::: "memory");
            __builtin_amdgcn_s_setprio(1);
#pragma unroll
            for (int ii = 0; ii < 2; ii++)
#pragma unroll
                for (int j = 0; j < 4; j++) {
                    acc[2 * p + ii][j] = __builtin_amdgcn_mfma_f32_16x16x32_bf16(
                            av[ii][0], bv0[j], acc[2 * p + ii][j], 0, 0, 0);
                    acc[2 * p + ii][j] = __builtin_amdgcn_mfma_f32_16x16x32_bf16(
                            av[ii][1], bv1[j], acc[2 * p + ii][j], 0, 0, 0);
                }
            __builtin_amdgcn_s_setprio(0);

            if (p == 3) {   // T4: counted wait -- tile t+1 landed, newest 2 halves in flight
                if (t + 2 < NT) asm volatile("s_waitcnt vmcnt(4)" ::: "memory");
                else           asm volatile("s_waitcnt vmcnt(0)" ::: "memory");
            }
            sbar();
        }
    }

    // epilogue: C/D layout col=lane&15, row=quad*4+reg (m89-verified)
    const int cb = tile_n + wn * 64 + l15;
    float bj[4];
#pragma unroll
    for (int j = 0; j < 4; j++) bj[j] = bias[cb + j * 16];
    const int r0 = tile_m + wm * 128 + quad * 4;
#pragma unroll
    for (int i = 0; i < 8; i++)
#pragma unroll
        for (int r = 0; r < 4; r++) {
            float* orow = out + (size_t)(r0 + i * 16 + r) * N;
#pragma unroll
            for (int j = 0; j < 4; j++)
                orow[cb + j * 16] = acc[i][j][r] + bj[j];
        }
}

extern "C" void kernel_launch(void* const* d_in, const int* in_sizes, int n_in,
                              void* d_out, int out_size, void* d_ws, size_t ws_size,
                              hipStream_t stream) {
    const float* enc   = (const float*)d_in[0];
    const int*   tgt   = (const int*)d_in[1];
    const int*   tlen  = (const int*)d_in[2];
    const float* st1   = (const float*)d_in[3];   // (2,B,H) h states
    const float* st2   = (const float*)d_in[4];   // (2,B,H) c states
    const float* wih0  = (const float*)d_in[5];
    const float* whh0  = (const float*)d_in[6];
    const float* bih0  = (const float*)d_in[7];
    const float* bhh0  = (const float*)d_in[8];
    const float* wih1  = (const float*)d_in[9];
    const float* whh1  = (const float*)d_in[10];
    const float* bih1  = (const float*)d_in[11];
    const float* bhh1  = (const float*)d_in[12];
    const float* emb   = (const float*)d_in[13];
    const float* wenc  = (const float*)d_in[14];
    const float* benc  = (const float*)d_in[15];
    const float* wpred = (const float*)d_in[16];
    const float* bpred = (const float*)d_in[17];
    const float* wout  = (const float*)d_in[18];
    const float* bout  = (const float*)d_in[19];

    float* out      = (float*)d_out;
    float* out_tlen = out + (size_t)B_ * T_ * V_;
    float* h0 = out_tlen + B_;            // output_states_1[0]
    float* h1 = h0 + B_ * H_;             // output_states_1[1]
    float* c0 = h1 + B_ * H_;             // output_states_2[0]
    float* c1 = c0 + B_ * H_;             // output_states_2[1]

    // workspace layout (~44.1 MB used at the front)
    unsigned short* encB  = (unsigned short*)d_ws;                 // 16384*512 bf16
    unsigned short* pB    = encB + (size_t)B_ * T_ * DE_;          // 16384*640 bf16
    unsigned short* woutB = pB + (size_t)B_ * T_ * J_;             // 4096*640 bf16
    unsigned short* wencB = woutB + (size_t)V_ * J_;               // 640*512 bf16
    float* gates = (float*)(wencB + (size_t)J_ * DE_);             // 32*2560 f32
    float* gvec  = gates + B_ * 4 * H_;                            // 32*640 f32

    // === ROUND-5 DIFFERENTIAL: the chain+GEMM1 below runs 1 (real) + 2 (replay) times.
    // Every kernel is a pure function of stable inputs -> replays are idempotent.
    // t(chain+GEMM1) = (dur_us - 517.3) / 2.  GEMM2 byte-frozen (105.3 us known).
    for (int rep = 0; rep < 3; rep++) {
        // weight converts + encoder transpose (independent)
        conv_f32_bf16_k<<<(V_ * J_ + 255) / 256, 256, 0, stream>>>(wout, woutB, V_ * J_);
        conv_f32_bf16_k<<<(J_ * DE_ + 255) / 256, 256, 0, stream>>>(wenc, wencB, J_ * DE_);
        enc_transpose_k<<<dim3(T_ / 32, DE_ / 32, B_), 256, 0, stream>>>(enc, encB);

        // LSTM layer 0 (x = embed[targets])
        lstm_gates_k<<<4 * H_, 64, 0, stream>>>(nullptr, tgt, emb, st1, wih0, whh0, bih0, bhh0, gates);
        lstm_update_k<<<(B_ * H_ + 255) / 256, 256, 0, stream>>>(gates, st2, h0, c0, tlen, out_tlen);
        // LSTM layer 1 (x = h0)
        lstm_gates_k<<<4 * H_, 64, 0, stream>>>(h0, nullptr, nullptr, st1 + B_ * H_, wih1, whh1, bih1, bhh1, gates);
        lstm_update_k<<<(B_ * H_ + 255) / 256, 256, 0, stream>>>(gates, st2 + B_ * H_, h1, c1, nullptr, nullptr);
        // g = h1 @ W_pred^T + b_pred
        pred_g_k<<<J_, 64, 0, stream>>>(h1, wpred, bpred, gvec);

        // P = bf16(relu(enc @ W_enc^T + b_enc + g))   [M=16384, N=640, K=512]
        gemm_bt_k<DE_, 1><<<dim3(J_ / 128, (B_ * T_) / 128), 256, 0, stream>>>(
            encB, wencB, benc, gvec, nullptr, pB, J_);
    }

    // out = P @ W_out^T + b_out                   [M=16384, N=4096, K=640]
    gemm256_k<B_ * T_, V_, J_><<<dim3((B_ * T_ / 256) * (V_ / 256)), 512, 0, stream>>>(
        pB, woutB, bout, out);
}

// Round 7
// 571.409 us; speedup vs baseline: 1.2864x; 1.2864x over previous
//
#include <hip/hip_runtime.h>
#include <stdint.h>

// Problem dims
#define B_  32
#define T_  512
#define DE_ 512
#define H_  640
#define V_  4096
#define J_  640

typedef __attribute__((ext_vector_type(4))) float  f32x4;
typedef __attribute__((ext_vector_type(8))) __bf16 bf16x8;

typedef __attribute__((address_space(3))) void LdsV;
typedef __attribute__((address_space(1))) void GloV;

__device__ __forceinline__ unsigned short f2bf(float f) {
    uint32_t u = __builtin_bit_cast(uint32_t, f);
    u += 0x7fffu + ((u >> 16) & 1u);   // round-to-nearest-even
    return (unsigned short)(u >> 16);
}

// ---------------- merged fp32 -> bf16 weight converts (wout then wenc) ----------------
__global__ void conv2_f32_bf16_k(const float* __restrict__ srcA, unsigned short* __restrict__ dstA, int nA,
                                 const float* __restrict__ srcB, unsigned short* __restrict__ dstB, int nB) {
    int i = blockIdx.x * blockDim.x + threadIdx.x;
    if (i < nA) dstA[i] = f2bf(srcA[i]);
    else if (i < nA + nB) dstB[i - nA] = f2bf(srcB[i - nA]);
}

// ---------------- encoder (B,D,T) -> bf16 (B*T, D) transpose ----------------
__global__ void enc_transpose_k(const float* __restrict__ enc,
                                unsigned short* __restrict__ out) {
    __shared__ float tile[32][33];
    int b  = blockIdx.z;
    int t0 = blockIdx.x * 32, d0 = blockIdx.y * 32;
    int tx = threadIdx.x & 31;
    int ty = (threadIdx.x >> 5) * 4;
    const float* src = enc + ((size_t)b * DE_ + d0) * T_ + t0;
#pragma unroll
    for (int i = 0; i < 4; i++)
        tile[ty + i][tx] = src[(size_t)(ty + i) * T_ + tx];  // coalesced over t
    __syncthreads();
    unsigned short* dst = out + ((size_t)b * T_ + t0) * DE_ + d0;
#pragma unroll
    for (int i = 0; i < 4; i++)
        dst[(size_t)(ty + i) * DE_ + tx] = f2bf(tile[tx][ty + i]);  // coalesced over d
}

// ---------------- fused LSTM layer: gates + pointwise update in one kernel ----------------
// grid = H_ blocks (one j each), 256 threads = 4 waves; wave w computes gate row n = w*H_ + j
// for all 32 batches (weights register-resident, shuffle reduce), drops results in LDS,
// then 32 threads do the sigmoid/tanh update. Replaces lstm_gates_k + lstm_update_k.
__global__ void lstm_fused_k(const float* __restrict__ x, const int* __restrict__ tok,
                             const float* __restrict__ emb, const float* __restrict__ h_in,
                             const float* __restrict__ c_in,
                             const float* __restrict__ wih, const float* __restrict__ whh,
                             const float* __restrict__ bih, const float* __restrict__ bhh,
                             float* __restrict__ h_out, float* __restrict__ c_out,
                             const int* __restrict__ tlen, float* __restrict__ tlen_out) {
    const int j = blockIdx.x;
    const int w = threadIdx.x >> 6, lane = threadIdx.x & 63;
    const int n = w * H_ + j;
    __shared__ float sm[4][B_];
    float wi[10], wh[10];
#pragma unroll
    for (int i = 0; i < 10; i++) {
        wi[i] = wih[(size_t)n * H_ + lane + 64 * i];   // coalesced
        wh[i] = whh[(size_t)n * H_ + lane + 64 * i];
    }
    const float bias = bih[n] + bhh[n];
    for (int b = 0; b < B_; b++) {
        const float* xr = tok ? (emb + (size_t)tok[b] * H_) : (x + (size_t)b * H_);
        const float* hr = h_in + (size_t)b * H_;
        float s = 0.f;
#pragma unroll
        for (int i = 0; i < 10; i++)
            s += wi[i] * xr[lane + 64 * i] + wh[i] * hr[lane + 64 * i];
#pragma unroll
        for (int off = 32; off > 0; off >>= 1)
            s += __shfl_down(s, off, 64);
        if (lane == 0) sm[w][b] = s + bias;
    }
    __syncthreads();
    if (threadIdx.x < B_) {
        const int b = threadIdx.x;
        float ig = 1.f / (1.f + expf(-sm[0][b]));
        float fg = 1.f / (1.f + expf(-sm[1][b]));
        float gg = tanhf(sm[2][b]);
        float og = 1.f / (1.f + expf(-sm[3][b]));
        float c  = fg * c_in[(size_t)b * H_ + j] + ig * gg;
        h_out[(size_t)b * H_ + j] = og * tanhf(c);
        c_out[(size_t)b * H_ + j] = c;
        if (tlen_out != nullptr && blockIdx.x == 0) tlen_out[b] = (float)tlen[b];
    }
}

// ---------------- g[b][j] = h1_b . wpred[j] + bpred[j] ----------------
__global__ void pred_g_k(const float* __restrict__ h1, const float* __restrict__ wp,
                         const float* __restrict__ bp, float* __restrict__ g) {
    int j = blockIdx.x, lane = threadIdx.x;
    float w[10];
#pragma unroll
    for (int i = 0; i < 10; i++) w[i] = wp[(size_t)j * H_ + lane + 64 * i];
    for (int b = 0; b < B_; b++) {
        const float* hr = h1 + (size_t)b * H_;
        float s = 0.f;
#pragma unroll
        for (int i = 0; i < 10; i++) s += w[i] * hr[lane + 64 * i];
#pragma unroll
        for (int off = 32; off > 0; off >>= 1)
            s += __shfl_down(s, off, 64);
        if (lane == 0) g[(size_t)b * J_ + j] = s + bp[j];
    }
}

// ---------------- m97-style bf16 MFMA GEMM, C = A (MxK) * B^T (NxK) ----------------
// Used for GEMM1 (kept to isolate gemm_v3 risk to GEMM2).
template <int K, int EPI>
__global__ __launch_bounds__(256) void gemm_bt_k(
        const unsigned short* __restrict__ A, const unsigned short* __restrict__ Bm,
        const float* __restrict__ bias, const float* __restrict__ g,
        float* __restrict__ outF, unsigned short* __restrict__ outU, int ldn) {
    __shared__ __align__(16) unsigned short As[128 * 32];
    __shared__ __align__(16) unsigned short Bs[128 * 32];
    const int tid  = threadIdx.x;
    const int w    = tid >> 6;          // wave 0..3
    const int lane = tid & 63;
    const int tile_n = blockIdx.x * 128;
    const int tile_m = blockIdx.y * 128;
    const int wm = w & 1, wn = w >> 1;  // wave -> 64x64 quadrant
    const int l15 = lane & 15, quad = lane >> 4;
    const int lr = lane >> 2, lc = lane & 3;  // staging: row-in-chunk, 16B slot

    f32x4 zero = {0.f, 0.f, 0.f, 0.f};
    f32x4 acc[4][4];
#pragma unroll
    for (int i = 0; i < 4; i++)
#pragma unroll
        for (int j = 0; j < 4; j++) acc[i][j] = zero;

    for (int k0 = 0; k0 < K; k0 += 32) {
#pragma unroll
        for (int cc = 0; cc < 2; cc++) {
            const int c = 2 * w + cc;
            const char* ga = (const char*)(A + (size_t)(tile_m + 16 * c + lr) * K)
                             + (size_t)k0 * 2 + lc * 16;
            __builtin_amdgcn_global_load_lds((const GloV*)ga,
                    (LdsV*)((char*)As + c * 1024), 16, 0, 0);
            const char* gb = (const char*)(Bm + (size_t)(tile_n + 16 * c + lr) * K)
                             + (size_t)k0 * 2 + lc * 16;
            __builtin_amdgcn_global_load_lds((const GloV*)gb,
                    (LdsV*)((char*)Bs + c * 1024), 16, 0, 0);
        }
        __syncthreads();

        bf16x8 av[4], bv[4];
#pragma unroll
        for (int i = 0; i < 4; i++) {
            av[i] = *(const bf16x8*)&As[(wm * 64 + i * 16 + l15) * 32 + quad * 8];
            bv[i] = *(const bf16x8*)&Bs[(wn * 64 + i * 16 + l15) * 32 + quad * 8];
        }
#pragma unroll
        for (int i = 0; i < 4; i++)
#pragma unroll
            for (int j = 0; j < 4; j++)
                acc[i][j] = __builtin_amdgcn_mfma_f32_16x16x32_bf16(av[i], bv[j], acc[i][j], 0, 0, 0);
        __syncthreads();
    }

#pragma unroll
    for (int i = 0; i < 4; i++) {
        const int mb = tile_m + wm * 64 + i * 16 + quad * 4;
#pragma unroll
        for (int j = 0; j < 4; j++) {
            const int n = tile_n + wn * 64 + j * 16 + l15;
#pragma unroll
            for (int r = 0; r < 4; r++) {
                float v = acc[i][j][r] + bias[n];
                if (EPI == 0) {
                    outF[(size_t)(mb + r) * ldn + n] = v;
                } else {
                    v += g[(size_t)((mb + r) >> 9) * J_ + n];
                    outU[(size_t)(mb + r) * ldn + n] = f2bf(fmaxf(v, 0.f));
                }
            }
        }
    }
}

// ---------------- GEMM2 v3: 256x128 tile, BK=32, 2 blocks/CU co-resident ----------------
// C = A (MxK) * B^T (NxK) + bias, fp32 out. 8 waves (4M x 2N quadrants of 64x64).
// LDS 48 KiB double-buffered -> 2 blocks/CU (96 KiB), VGPR capped 128 (launch_bounds 512,4):
// the co-resident block's K-loop overlaps this block's epilogue store drain (the ~10 us/gen
// serialization that pinned the round-3 1-block/CU kernel at 105 us / 816 TF).
// Sync: ONE plain __syncthreads() per K-tile (classic m97 double-buffer). It drains
// vmcnt(0)+lgkmcnt(0) -- conservative, race-free; the per-iteration stall is hidden by the
// co-resident block (m114 wave-level overlap), not by counted vmcnt.
// LDS layout SLOT-MAJOR: As[slot s][256 rows][16B], s = 16B k-chunk of the BK=32 window.
// Staging is linear global_load_lds (dest = uniform base + lane*16; per-lane global source
// stride K2 -- rule #21 safe, no swizzle). Frag reads: each 16-lane quad reads 256B
// contiguous -> all 32 banks covered evenly, no pathological conflict.
template <int M, int N, int K>
__global__ __launch_bounds__(512, 4) void gemm_v3_k(
        const unsigned short* __restrict__ A, const unsigned short* __restrict__ Bm,
        const float* __restrict__ bias, float* __restrict__ out) {
    __shared__ __align__(16) char lds[49152];    // 2 x (As 16K + Bs 8K)
    constexpr int NT  = K / 32;
    constexpr int K2  = K * 2;                   // global row stride in bytes
    constexpr int NTN = N / 128;
    constexpr int NWG = (M / 256) * NTN;         // 2048 (divisible by 8)

    // T1: XCD-aware bijective swizzle; consecutive swz in a chunk share the A m-panel.
    const int bid = blockIdx.x;
    const int swz = (bid & 7) * (NWG / 8) + (bid >> 3);
    const int tile_n = (swz % NTN) * 128;
    const int tile_m = (swz / NTN) * 256;

    const int tid  = threadIdx.x;
    const int w    = tid >> 6;                   // wave 0..7
    const int l    = tid & 63;
    const int wm   = w >> 1;                     // 0..3 -> 64-row band
    const int wn   = w & 1;                      // 0..1 -> 64-col band
    const int l15  = l & 15, quad = l >> 4;

    // staging (per wave): A loads idx = 2w, 2w+1 (16 total: rowgrp=idx>>2, slot=idx&3);
    // B load: rowgrp=w>>2, slot=w&3 (8 total).
    const int ai0 = 2 * w, ai1 = 2 * w + 1;
    const char* srcA0 = (const char*)A + (size_t)(tile_m + (ai0 >> 2) * 64 + l) * K2 + (ai0 & 3) * 16;
    const char* srcA1 = (const char*)A + (size_t)(tile_m + (ai1 >> 2) * 64 + l) * K2 + (ai1 & 3) * 16;
    const char* srcB  = (const char*)Bm + (size_t)(tile_n + (w >> 2) * 64 + l) * K2 + (w & 3) * 16;
    const int dA0 = (ai0 & 3) * 4096 + (ai0 >> 2) * 1024;
    const int dA1 = (ai1 & 3) * 4096 + (ai1 >> 2) * 1024;
    const int dB  = 16384 + (w & 3) * 2048 + (w >> 2) * 1024;

    auto stage = [&](int kt) {
        char* base = lds + (kt & 1) * 24576;
        const int kb = kt * 64;
        __builtin_amdgcn_global_load_lds((const GloV*)(srcA0 + kb), (LdsV*)(base + dA0), 16, 0, 0);
        __builtin_amdgcn_global_load_lds((const GloV*)(srcA1 + kb), (LdsV*)(base + dA1), 16, 0, 0);
        __builtin_amdgcn_global_load_lds((const GloV*)(srcB  + kb), (LdsV*)(base + dB),  16, 0, 0);
    };

    // frag read offsets (slot-major): row wm*64+i*16+l15 at slot quad
    const int aoff = quad * 4096 + (wm * 64 + l15) * 16;
    const int boff = 16384 + quad * 2048 + (wn * 64 + l15) * 16;

    f32x4 acc[4][4];
    f32x4 zero = {0.f, 0.f, 0.f, 0.f};
#pragma unroll
    for (int i = 0; i < 4; i++)
#pragma unroll
        for (int j = 0; j < 4; j++) acc[i][j] = zero;

    stage(0);
    __syncthreads();                         // tile 0 landed (drains vmcnt) + all waves aligned

    for (int t = 0; t < NT; ++t) {
        if (t + 1 < NT) stage(t + 1);        // fills buf((t+1)&1); its last reads closed
                                             // by the sync at end of iteration t-1
        const char* base = lds + (t & 1) * 24576;
        bf16x8 av[4], bv[4];
#pragma unroll
        for (int i = 0; i < 4; i++) av[i] = *(const bf16x8*)(base + aoff + i * 256);
#pragma unroll
        for (int j = 0; j < 4; j++) bv[j] = *(const bf16x8*)(base + boff + j * 256);
#pragma unroll
        for (int i = 0; i < 4; i++)
#pragma unroll
            for (int j = 0; j < 4; j++)
                acc[i][j] = __builtin_amdgcn_mfma_f32_16x16x32_bf16(av[i], bv[j], acc[i][j], 0, 0, 0);
        __syncthreads();                     // drains tile t+1's loads; protects buf(t&1)
    }

    // epilogue: C/D layout col=lane&15, row=quad*4+reg (m89-verified)
    const int cb = tile_n + wn * 64 + l15;
    float bj[4];
#pragma unroll
    for (int j = 0; j < 4; j++) bj[j] = bias[cb + j * 16];
    const int r0 = tile_m + wm * 64 + quad * 4;
#pragma unroll
    for (int i = 0; i < 4; i++)
#pragma unroll
        for (int r = 0; r < 4; r++) {
            float* orow = out + (size_t)(r0 + i * 16 + r) * N;
#pragma unroll
            for (int j = 0; j < 4; j++)
                orow[cb + j * 16] = acc[i][j][r] + bj[j];
        }
}

extern "C" void kernel_launch(void* const* d_in, const int* in_sizes, int n_in,
                              void* d_out, int out_size, void* d_ws, size_t ws_size,
                              hipStream_t stream) {
    const float* enc   = (const float*)d_in[0];
    const int*   tgt   = (const int*)d_in[1];
    const int*   tlen  = (const int*)d_in[2];
    const float* st1   = (const float*)d_in[3];   // (2,B,H) h states
    const float* st2   = (const float*)d_in[4];   // (2,B,H) c states
    const float* wih0  = (const float*)d_in[5];
    const float* whh0  = (const float*)d_in[6];
    const float* bih0  = (const float*)d_in[7];
    const float* bhh0  = (const float*)d_in[8];
    const float* wih1  = (const float*)d_in[9];
    const float* whh1  = (const float*)d_in[10];
    const float* bih1  = (const float*)d_in[11];
    const float* bhh1  = (const float*)d_in[12];
    const float* emb   = (const float*)d_in[13];
    const float* wenc  = (const float*)d_in[14];
    const float* benc  = (const float*)d_in[15];
    const float* wpred = (const float*)d_in[16];
    const float* bpred = (const float*)d_in[17];
    const float* wout  = (const float*)d_in[18];
    const float* bout  = (const float*)d_in[19];

    float* out      = (float*)d_out;
    float* out_tlen = out + (size_t)B_ * T_ * V_;
    float* h0 = out_tlen + B_;            // output_states_1[0]
    float* h1 = h0 + B_ * H_;             // output_states_1[1]
    float* c0 = h1 + B_ * H_;             // output_states_2[0]
    float* c1 = c0 + B_ * H_;             // output_states_2[1]

    // workspace layout (~44.1 MB used at the front)
    unsigned short* encB  = (unsigned short*)d_ws;                 // 16384*512 bf16
    unsigned short* pB    = encB + (size_t)B_ * T_ * DE_;          // 16384*640 bf16
    unsigned short* woutB = pB + (size_t)B_ * T_ * J_;             // 4096*640 bf16
    unsigned short* wencB = woutB + (size_t)V_ * J_;               // 640*512 bf16
    float* gvec  = (float*)(wencB + (size_t)J_ * DE_);             // 32*640 f32

    // merged weight converts + encoder transpose (independent)
    conv2_f32_bf16_k<<<(V_ * J_ + J_ * DE_ + 255) / 256, 256, 0, stream>>>(
        wout, woutB, V_ * J_, wenc, wencB, J_ * DE_);
    enc_transpose_k<<<dim3(T_ / 32, DE_ / 32, B_), 256, 0, stream>>>(enc, encB);

    // LSTM layer 0 (x = embed[targets]) -- fused gates+update (+ tlen passthrough)
    lstm_fused_k<<<H_, 256, 0, stream>>>(nullptr, tgt, emb, st1, st2,
                                         wih0, whh0, bih0, bhh0, h0, c0, tlen, out_tlen);
    // LSTM layer 1 (x = h0)
    lstm_fused_k<<<H_, 256, 0, stream>>>(h0, nullptr, nullptr, st1 + B_ * H_, st2 + B_ * H_,
                                         wih1, whh1, bih1, bhh1, h1, c1, nullptr, nullptr);
    // g = h1 @ W_pred^T + b_pred
    pred_g_k<<<J_, 64, 0, stream>>>(h1, wpred, bpred, gvec);

    // P = bf16(relu(enc @ W_enc^T + b_enc + g))   [M=16384, N=640, K=512]
    gemm_bt_k<DE_, 1><<<dim3(J_ / 128, (B_ * T_) / 128), 256, 0, stream>>>(
        encB, wencB, benc, gvec, nullptr, pB, J_);

    // out = P @ W_out^T + b_out                   [M=16384, N=4096, K=640]
    gemm_v3_k<B_ * T_, V_, J_><<<dim3((B_ * T_ / 256) * (V_ / 128)), 512, 0, stream>>>(
        pB, woutB, bout, out);
}